// Round 6
// baseline (80.518 us; speedup 1.0000x reference)
//
#include <hip/hip_runtime.h>

typedef __attribute__((ext_vector_type(8))) short svec8;
typedef __attribute__((ext_vector_type(4))) float fvec4;

#define NB    4096
#define NN    6
#define FF    512
#define CC    256
#define KFULL 1024
#define MROWS (NB*NN)                 // 24576
#define AD_HALF ((size_t)MROWS*CC)    // 6291456 elements
#define NTOT  (NB*NN*NN)              // 147456

#define GLOAD16(gp, lp) __builtin_amdgcn_global_load_lds(                      \
    (const __attribute__((address_space(1))) unsigned int*)(gp),               \
    (__attribute__((address_space(3))) unsigned int*)(lp), 16, 0, 0)

__device__ __forceinline__ unsigned short f2bf(float f) {
    unsigned u = __float_as_uint(f);
    u += 0x7FFFu + ((u >> 16) & 1u);   // round-to-nearest-even
    return (unsigned short)(u >> 16);
}
__device__ __forceinline__ float bf2f(unsigned short h) {
    return __uint_as_float(((unsigned)h) << 16);
}

// ---------------- kernel 0: conv_w fp32->bf16 + zero stats ----------------
__global__ __launch_bounds__(256) void k_pre(const float* __restrict__ w,
                                             unsigned short* __restrict__ wbf,
                                             float* __restrict__ stats) {
    int g = blockIdx.x * 256 + threadIdx.x;   // grid 256 -> 65536 vec4 chunks
    fvec4 v = *(const fvec4*)(w + (size_t)g * 4);
    unsigned long long pk = (unsigned long long)f2bf(v[0])
                          | ((unsigned long long)f2bf(v[1]) << 16)
                          | ((unsigned long long)f2bf(v[2]) << 32)
                          | ((unsigned long long)f2bf(v[3]) << 48);
    *(unsigned long long*)(wbf + (size_t)g * 4) = pk;
    if (g < 512) stats[g] = 0.f;
}

// ---------------- kernel 1: GEMM both halves + fused per-channel stats ----------------
// grid 512 x 256 thr (2 blocks/CU for barrier-stall hiding). Block owns rows
// [mtile*48, +48) = 8 complete b-groups. Pass s=0: A-half; s=1: D-half.
// 4 waves, wave wv owns cols [wv*64, +64), all 48 rows (acc[3][4] per pass).
// Tail: re-read own AD tile (L2-hot) -> per-channel stats -> atomicAdd.
__global__ __launch_bounds__(256, 2) void k_gemm_fused(
        const float* __restrict__ x,
        const unsigned short* __restrict__ wbf,
        const float* __restrict__ conv_b,
        unsigned short* __restrict__ AD,
        float* __restrict__ stats) {
    __shared__ __align__(16) char lds[38912];   // A: 48x64 bf16 = 6KB @0, B: 256x64 bf16 = 32KB @6144
    const int tid = threadIdx.x;
    const int mtile = blockIdx.x;               // 0..511
    const int wv = tid >> 6;

    // --- A staging: 384 16B-chunks; unit0 = tid, unit1 = 256+tid (tid<128) ---
    const int row0 = tid >> 3, slot0 = tid & 7;
    const int row1 = 32 + (tid >> 3);           // only tid<128
    const int a_lds_u0 = row0 * 128 + ((slot0 * 16) ^ ((row0 & 7) << 4));
    const int a_lds_u1 = row1 * 128 + ((slot0 * 16) ^ ((row1 & 7) << 4));
    const bool has_u1 = (tid < 128);

    // --- fragment LDS offsets (pass-invariant) ---
    const int l = tid & 63;
    const int lrow = l & 15;
    const int lk = l >> 4;
    int abase[2], bbase[2];
#pragma unroll
    for (int ks = 0; ks < 2; ++ks) {
        int xr = (ks * 64 + lk * 16) ^ ((lrow & 7) << 4);
        abase[ks] = lrow * 128 + xr;
        bbase[ks] = 6144 + (wv * 64 + lrow) * 128 + xr;
    }

    const fvec4 vzero = {0.f, 0.f, 0.f, 0.f};
    fvec4 accA[3][4], accD[3][4];
#pragma unroll
    for (int mi = 0; mi < 3; ++mi)
#pragma unroll
        for (int ni = 0; ni < 4; ++ni) { accA[mi][ni] = vzero; accD[mi][ni] = vzero; }

#pragma unroll
    for (int s = 0; s < 2; ++s) {
        fvec4 (&acc)[3][4] = s ? accD : accA;

        // per-pass global A addresses
        int m0 = mtile * 48 + row0, b0 = m0 / 6, j0 = m0 - b0 * 6;
        const float* aptr0 = x + ((size_t)((b0 * 2 + s) * 6 + j0)) * FF + slot0 * 8;
        int m1 = mtile * 48 + row1, b1 = m1 / 6, j1 = m1 - b1 * 6;
        const float* aptr1 = x + ((size_t)((b1 * 2 + s) * 6 + j1)) * FF + slot0 * 8;

        // B staging: 2048 chunks / 256 thr = 8 gloads
        const unsigned short* bsrc[8];
        char* bdst[8];
#pragma unroll
        for (int i = 0; i < 8; ++i) {
            int ci = i * 256 + tid;
            int row = ci >> 3;
            int xslot = ci & 7;
            bsrc[i] = wbf + (size_t)row * KFULL + s * FF + ((xslot ^ (row & 7)) << 3);
            bdst[i] = lds + 6144 + i * 4096 + wv * 1024;   // wave-uniform base
        }

        fvec4 lo0 = *(const fvec4*)aptr0, hi0 = *(const fvec4*)(aptr0 + 4);
        fvec4 lo1 = vzero, hi1 = vzero;
        if (has_u1) { lo1 = *(const fvec4*)aptr1; hi1 = *(const fvec4*)(aptr1 + 4); }

        for (int kt = 0; kt < 8; ++kt) {
            const int k0 = kt * 64;
            {
                svec8 v;
                v[0] = (short)f2bf(lo0[0]); v[1] = (short)f2bf(lo0[1]);
                v[2] = (short)f2bf(lo0[2]); v[3] = (short)f2bf(lo0[3]);
                v[4] = (short)f2bf(hi0[0]); v[5] = (short)f2bf(hi0[1]);
                v[6] = (short)f2bf(hi0[2]); v[7] = (short)f2bf(hi0[3]);
                *(svec8*)(lds + a_lds_u0) = v;
            }
            if (has_u1) {
                svec8 v;
                v[0] = (short)f2bf(lo1[0]); v[1] = (short)f2bf(lo1[1]);
                v[2] = (short)f2bf(lo1[2]); v[3] = (short)f2bf(lo1[3]);
                v[4] = (short)f2bf(hi1[0]); v[5] = (short)f2bf(hi1[1]);
                v[6] = (short)f2bf(hi1[2]); v[7] = (short)f2bf(hi1[3]);
                *(svec8*)(lds + a_lds_u1) = v;
            }
#pragma unroll
            for (int i = 0; i < 8; ++i) GLOAD16(bsrc[i] + k0, bdst[i]);
            __syncthreads();
            if (kt < 7) {
                const float* p0 = aptr0 + (kt + 1) * 64;
                lo0 = *(const fvec4*)p0; hi0 = *(const fvec4*)(p0 + 4);
                if (has_u1) {
                    const float* p1 = aptr1 + (kt + 1) * 64;
                    lo1 = *(const fvec4*)p1; hi1 = *(const fvec4*)(p1 + 4);
                }
            }
#pragma unroll
            for (int ks = 0; ks < 2; ++ks) {
                svec8 af[3], bfr[4];
#pragma unroll
                for (int mi = 0; mi < 3; ++mi) af[mi] = *(const svec8*)(lds + abase[ks] + mi * 2048);
#pragma unroll
                for (int ni = 0; ni < 4; ++ni) bfr[ni] = *(const svec8*)(lds + bbase[ks] + ni * 2048);
#pragma unroll
                for (int mi = 0; mi < 3; ++mi)
#pragma unroll
                    for (int ni = 0; ni < 4; ++ni)
                        acc[mi][ni] = __builtin_amdgcn_mfma_f32_16x16x32_bf16(
                            af[mi], bfr[ni], acc[mi][ni], 0, 0, 0);
            }
            __syncthreads();
        }

        // epilogue for this pass: C/D layout col=lane&15, row=(lane>>4)*4+reg
        unsigned short* op = AD + (size_t)s * AD_HALF;
#pragma unroll
        for (int mi = 0; mi < 3; ++mi) {
#pragma unroll
            for (int j = 0; j < 4; ++j) {
                int r = mi * 16 + lk * 4 + j;
                size_t m = (size_t)(mtile * 48 + r);
#pragma unroll
                for (int ni = 0; ni < 4; ++ni) {
                    int c = wv * 64 + ni * 16 + lrow;
                    op[m * 256 + c] = f2bf(acc[mi][ni][j]);
                }
            }
        }
    }

    // ---- fused stats tail: re-read own tile (L2-hot), per-channel atomics ----
    asm volatile("s_waitcnt vmcnt(0)" ::: "memory");
    __syncthreads();   // all waves' AD stores drained to L2
    {
        const int c = tid;   // one channel per thread
        const float bias = conv_b[c];
        float s1 = 0.f, s2 = 0.f;
        for (int g = 0; g < 8; ++g) {
            size_t m0 = (size_t)(mtile * 48 + g * 6);
            const unsigned short* ga = AD + m0 * 256 + c;
            const unsigned short* gd = AD + AD_HALF + m0 * 256 + c;
            float a[6], d[6];
#pragma unroll
            for (int j = 0; j < 6; ++j) { a[j] = bf2f(ga[j * 256]); d[j] = bf2f(gd[j * 256]); }
#pragma unroll
            for (int j = 0; j < 6; ++j) {
                float aj = a[j] + bias;
#pragma unroll
                for (int e = 0; e < 6; ++e) {
                    float h = fmaxf(aj + d[e], 0.f);
                    s1 += h;
                    s2 = fmaf(h, h, s2);
                }
            }
        }
        atomicAdd(&stats[c], s1);
        atomicAdd(&stats[256 + c], s2);
    }
}

// ---------------- kernel 2: normalize + write output (float4 stores) ----------------
__global__ __launch_bounds__(256) void k_out(const unsigned short* __restrict__ AD,
                                             const float* __restrict__ conv_b,
                                             const float* __restrict__ gamma,
                                             const float* __restrict__ beta,
                                             const float* __restrict__ stats,
                                             float* __restrict__ out) {
    __shared__ float Al[6][260], Dl[6][260];
    __shared__ float sc[256], sh[256], bi[256];
    const int t = threadIdx.x;
    const int b = blockIdx.x;
    const unsigned short* ga = AD + (size_t)b * 1536;
    const unsigned short* gd = AD + AD_HALF + (size_t)b * 1536;
#pragma unroll
    for (int i = 0; i < 6; ++i) {
        Al[i][t] = bf2f(ga[i * 256 + t]);
        Dl[i][t] = bf2f(gd[i * 256 + t]);
    }
    const float inv_n = 1.0f / (float)NTOT;
    float mean = stats[t] * inv_n;
    float var = fmaf(-mean, mean, stats[256 + t] * inv_n);
    float scale = gamma[t] * rsqrtf(var + 1e-5f);
    sc[t] = scale;
    sh[t] = fmaf(-mean, scale, beta[t]);
    bi[t] = conv_b[t];
    __syncthreads();
    float* ob = out + (size_t)b * 9216;
#pragma unroll
    for (int it = 0; it < 9; ++it) {
        int idx0 = it * 1024 + t * 4;
        fvec4 v;
#pragma unroll
        for (int q = 0; q < 4; ++q) {
            int idx = idx0 + q;
            int c = idx / 36;
            int r = idx - c * 36;
            int ii = r / 6;
            int j = r - ii * 6;
            int d = j - ii; if (d < 0) d += 6;
            float h = fmaxf(Al[j][c] + Dl[d][c] + bi[c], 0.f);
            v[q] = fmaf(h, sc[c], sh[c]);
        }
        __builtin_nontemporal_store(v, (fvec4*)(ob + idx0));
    }
}

extern "C" void kernel_launch(void* const* d_in, const int* in_sizes, int n_in,
                              void* d_out, int out_size, void* d_ws, size_t ws_size,
                              hipStream_t stream) {
    const float* x      = (const float*)d_in[0];
    const float* conv_w = (const float*)d_in[1];
    const float* conv_b = (const float*)d_in[2];
    const float* gamma  = (const float*)d_in[3];
    const float* beta   = (const float*)d_in[4];
    float* out = (float*)d_out;

    char* ws = (char*)d_ws;
    unsigned short* wbf = (unsigned short*)ws;                       // 512 KB
    unsigned short* AD  = (unsigned short*)(ws + 524288);            // 25165824 B
    float* stats        = (float*)(ws + 524288 + 25165824);          // 2 KB

    k_pre<<<256, 256, 0, stream>>>(conv_w, wbf, stats);
    k_gemm_fused<<<512, 256, 0, stream>>>(x, wbf, conv_b, AD, stats);
    k_out<<<4096, 256, 0, stream>>>(AD, conv_b, gamma, beta, stats, out);
}

// Round 7
// 75.407 us; speedup vs baseline: 1.0678x; 1.0678x over previous
//
#include <hip/hip_runtime.h>

typedef __attribute__((ext_vector_type(8))) short svec8;
typedef __attribute__((ext_vector_type(4))) float fvec4;

#define NB    4096
#define NN    6
#define FF    512
#define CC    256
#define KFULL 1024
#define MROWS (NB*NN)                 // 24576
#define AD_HALF ((size_t)MROWS*CC)    // 6291456 elements
#define NTOT  (NB*NN*NN)              // 147456

// LDS map (k_gemm_fused): Abuf0 @0 (12KB), Abuf1 @12288, Bbuf0 @24576 (32KB), Bbuf1 @57344. total 90112.
#define ABUF_STRIDE 12288
#define BOFF        24576
#define BBUF_STRIDE 32768

#define GLOAD16(gp, lp) __builtin_amdgcn_global_load_lds(                      \
    (const __attribute__((address_space(1))) unsigned int*)(gp),               \
    (__attribute__((address_space(3))) unsigned int*)(lp), 16, 0, 0)

__device__ __forceinline__ unsigned short f2bf(float f) {
    unsigned u = __float_as_uint(f);
    u += 0x7FFFu + ((u >> 16) & 1u);   // round-to-nearest-even
    return (unsigned short)(u >> 16);
}
__device__ __forceinline__ float bf2f(unsigned short h) {
    return __uint_as_float(((unsigned)h) << 16);
}
__device__ __forceinline__ svec8 cvt8(fvec4 lo, fvec4 hi) {
    svec8 v;
    v[0] = (short)f2bf(lo[0]); v[1] = (short)f2bf(lo[1]);
    v[2] = (short)f2bf(lo[2]); v[3] = (short)f2bf(lo[3]);
    v[4] = (short)f2bf(hi[0]); v[5] = (short)f2bf(hi[1]);
    v[6] = (short)f2bf(hi[2]); v[7] = (short)f2bf(hi[3]);
    return v;
}

// ---------------- kernel 0: conv_w fp32->bf16 + zero stats ----------------
__global__ __launch_bounds__(256) void k_pre(const float* __restrict__ w,
                                             unsigned short* __restrict__ wbf,
                                             float* __restrict__ stats) {
    int g = blockIdx.x * 256 + threadIdx.x;   // grid 256 -> 65536 vec4 chunks
    fvec4 v = *(const fvec4*)(w + (size_t)g * 4);
    unsigned long long pk = (unsigned long long)f2bf(v[0])
                          | ((unsigned long long)f2bf(v[1]) << 16)
                          | ((unsigned long long)f2bf(v[2]) << 32)
                          | ((unsigned long long)f2bf(v[3]) << 48);
    *(unsigned long long*)(wbf + (size_t)g * 4) = pk;
    if (g < 512) stats[g] = 0.f;
}

// ---------------- kernel 1: GEMM both halves + fused stats, dbuf pipeline ----------------
// grid 256 x 512 thr (1 block/CU, 8 waves). Block owns rows [mtile*96,+96) =
// 16 b-groups. Pass s=0: A-half, s=1: D-half. Double-buffered A/B LDS:
// per kt: issue B[kt+1] gloads + A[kt+1] reg-loads BEFORE MFMA[kt]; write
// A[kt+1] to LDS after MFMA (latency covered); one barrier per kt.
__global__ __launch_bounds__(512, 1) void k_gemm_fused(
        const float* __restrict__ x,
        const unsigned short* __restrict__ wbf,
        const float* __restrict__ conv_b,
        unsigned short* __restrict__ AD,
        float* __restrict__ stats) {
    __shared__ __align__(16) char lds[90112];
    const int tid = threadIdx.x;
    const int mtile = blockIdx.x;               // 0..255
    const int wv = tid >> 6;
    const int cg = wv & 3;                      // col-group: 64 cols
    const int rh = wv >> 2;                     // row-half: 48 rows

    // A staging: 768 16B-chunks; unit0 = tid (rows 0..63), unit1 (tid<256, rows 64..95)
    const int row0 = tid >> 3, slot0 = tid & 7;
    const int row1 = 64 + (tid >> 3);
    const bool has_u1 = (tid < 256);
    const int a_off_u0 = row0 * 128 + ((slot0 * 16) ^ ((row0 & 7) << 4));
    const int a_off_u1 = row1 * 128 + ((slot0 * 16) ^ ((row1 & 7) << 4));

    // fragment LDS offsets (pass/buffer-invariant parts)
    const int l = tid & 63;
    const int lrow = l & 15;
    const int lk = l >> 4;
    int abase[2], bbase[2];
#pragma unroll
    for (int ks = 0; ks < 2; ++ks) {
        int xr = (ks * 64 + lk * 16) ^ ((lrow & 7) << 4);
        abase[ks] = (rh * 48 + lrow) * 128 + xr;
        bbase[ks] = BOFF + (cg * 64 + lrow) * 128 + xr;
    }

    const fvec4 vzero = {0.f, 0.f, 0.f, 0.f};
    fvec4 accA[3][4], accD[3][4];
#pragma unroll
    for (int mi = 0; mi < 3; ++mi)
#pragma unroll
        for (int ni = 0; ni < 4; ++ni) { accA[mi][ni] = vzero; accD[mi][ni] = vzero; }

#pragma unroll
    for (int s = 0; s < 2; ++s) {
        fvec4 (&acc)[3][4] = s ? accD : accA;

        // per-pass global A addresses
        int m0 = mtile * 96 + row0, b0 = m0 / 6, j0 = m0 - b0 * 6;
        const float* aptr0 = x + ((size_t)((b0 * 2 + s) * 6 + j0)) * FF + slot0 * 8;
        int m1 = mtile * 96 + row1, b1 = m1 / 6, j1 = m1 - b1 * 6;
        const float* aptr1 = x + ((size_t)((b1 * 2 + s) * 6 + j1)) * FF + slot0 * 8;

        // B staging: 2048 chunks / 512 thr = 4 gloads per kt
        const unsigned short* bsrc[4];
#pragma unroll
        for (int i = 0; i < 4; ++i) {
            int ci = i * 512 + tid;
            int row = ci >> 3;
            int xslot = ci & 7;
            bsrc[i] = wbf + (size_t)row * KFULL + s * FF + ((xslot ^ (row & 7)) << 3);
        }

        // ---- prologue: stage tile kt=0 into buf0 ----
#pragma unroll
        for (int i = 0; i < 4; ++i)
            GLOAD16(bsrc[i], lds + BOFF + i * 8192 + wv * 1024);
        {
            fvec4 lo0 = *(const fvec4*)aptr0, hi0 = *(const fvec4*)(aptr0 + 4);
            *(svec8*)(lds + a_off_u0) = cvt8(lo0, hi0);
            if (has_u1) {
                fvec4 lo1 = *(const fvec4*)aptr1, hi1 = *(const fvec4*)(aptr1 + 4);
                *(svec8*)(lds + a_off_u1) = cvt8(lo1, hi1);
            }
        }
        __syncthreads();

#pragma unroll
        for (int kt = 0; kt < 8; ++kt) {
            const int cur = kt & 1, nxt = cur ^ 1;
            fvec4 nlo0, nhi0, nlo1, nhi1;
            // 1) issue next-tile loads BEFORE compute
            if (kt < 7) {
#pragma unroll
                for (int i = 0; i < 4; ++i)
                    GLOAD16(bsrc[i] + (kt + 1) * 64,
                            lds + BOFF + nxt * BBUF_STRIDE + i * 8192 + wv * 1024);
                const float* p0 = aptr0 + (kt + 1) * 64;
                nlo0 = *(const fvec4*)p0; nhi0 = *(const fvec4*)(p0 + 4);
                if (has_u1) {
                    const float* p1 = aptr1 + (kt + 1) * 64;
                    nlo1 = *(const fvec4*)p1; nhi1 = *(const fvec4*)(p1 + 4);
                }
            }
            // 2) MFMA on current buffers
#pragma unroll
            for (int ks = 0; ks < 2; ++ks) {
                svec8 af[3], bfr[4];
#pragma unroll
                for (int mi = 0; mi < 3; ++mi)
                    af[mi] = *(const svec8*)(lds + cur * ABUF_STRIDE + abase[ks] + mi * 2048);
#pragma unroll
                for (int ni = 0; ni < 4; ++ni)
                    bfr[ni] = *(const svec8*)(lds + cur * BBUF_STRIDE + bbase[ks] + ni * 2048);
#pragma unroll
                for (int mi = 0; mi < 3; ++mi)
#pragma unroll
                    for (int ni = 0; ni < 4; ++ni)
                        acc[mi][ni] = __builtin_amdgcn_mfma_f32_16x16x32_bf16(
                            af[mi], bfr[ni], acc[mi][ni], 0, 0, 0);
            }
            // 3) write next A tile (reg loads covered by MFMA phase)
            if (kt < 7) {
                *(svec8*)(lds + nxt * ABUF_STRIDE + a_off_u0) = cvt8(nlo0, nhi0);
                if (has_u1)
                    *(svec8*)(lds + nxt * ABUF_STRIDE + a_off_u1) = cvt8(nlo1, nhi1);
            }
            __syncthreads();
        }

        // epilogue for this pass: C/D layout col=lane&15, row=(lane>>4)*4+reg
        unsigned short* op = AD + (size_t)s * AD_HALF;
#pragma unroll
        for (int mi = 0; mi < 3; ++mi) {
#pragma unroll
            for (int j = 0; j < 4; ++j) {
                int r = rh * 48 + mi * 16 + lk * 4 + j;
                size_t m = (size_t)(mtile * 96 + r);
#pragma unroll
                for (int ni = 0; ni < 4; ++ni) {
                    int c = cg * 64 + ni * 16 + lrow;
                    op[m * 256 + c] = f2bf(acc[mi][ni][j]);
                }
            }
        }
    }

    // ---- fused stats tail: re-read own tile (L2-hot), reduce, atomic ----
    asm volatile("s_waitcnt vmcnt(0)" ::: "memory");
    __syncthreads();   // all waves' AD stores drained to L2
    {
        const int c = tid & 255;
        const int half = tid >> 8;
        const float bias = conv_b[c];
        float s1 = 0.f, s2 = 0.f;
        for (int bb = 0; bb < 8; ++bb) {
            int bl = half * 8 + bb;
            size_t m0 = (size_t)(mtile * 96 + bl * 6);
            const unsigned short* ga = AD + m0 * 256 + c;
            const unsigned short* gd = AD + AD_HALF + m0 * 256 + c;
            float a[6], d[6];
#pragma unroll
            for (int j = 0; j < 6; ++j) { a[j] = bf2f(ga[j * 256]); d[j] = bf2f(gd[j * 256]); }
#pragma unroll
            for (int j = 0; j < 6; ++j) {
                float aj = a[j] + bias;
#pragma unroll
                for (int e = 0; e < 6; ++e) {
                    float h = fmaxf(aj + d[e], 0.f);
                    s1 += h;
                    s2 = fmaf(h, h, s2);
                }
            }
        }
        float* red = (float*)lds;
        red[half * 256 + c] = s1;
        red[512 + half * 256 + c] = s2;
        __syncthreads();
        if (tid < 256) {
            atomicAdd(&stats[tid], red[tid] + red[256 + tid]);
            atomicAdd(&stats[256 + tid], red[512 + tid] + red[768 + tid]);
        }
    }
}

// ---------------- kernel 2: normalize + write output (float4 stores) ----------------
__global__ __launch_bounds__(256) void k_out(const unsigned short* __restrict__ AD,
                                             const float* __restrict__ conv_b,
                                             const float* __restrict__ gamma,
                                             const float* __restrict__ beta,
                                             const float* __restrict__ stats,
                                             float* __restrict__ out) {
    __shared__ float Al[6][260], Dl[6][260];
    __shared__ float sc[256], sh[256], bi[256];
    const int t = threadIdx.x;
    const int b = blockIdx.x;
    const unsigned short* ga = AD + (size_t)b * 1536;
    const unsigned short* gd = AD + AD_HALF + (size_t)b * 1536;
#pragma unroll
    for (int i = 0; i < 6; ++i) {
        Al[i][t] = bf2f(ga[i * 256 + t]);
        Dl[i][t] = bf2f(gd[i * 256 + t]);
    }
    const float inv_n = 1.0f / (float)NTOT;
    float mean = stats[t] * inv_n;
    float var = fmaf(-mean, mean, stats[256 + t] * inv_n);
    float scale = gamma[t] * rsqrtf(var + 1e-5f);
    sc[t] = scale;
    sh[t] = fmaf(-mean, scale, beta[t]);
    bi[t] = conv_b[t];
    __syncthreads();
    float* ob = out + (size_t)b * 9216;
#pragma unroll
    for (int it = 0; it < 9; ++it) {
        int idx0 = it * 1024 + t * 4;
        fvec4 v;
#pragma unroll
        for (int q = 0; q < 4; ++q) {
            int idx = idx0 + q;
            int c = idx / 36;
            int r = idx - c * 36;
            int ii = r / 6;
            int j = r - ii * 6;
            int d = j - ii; if (d < 0) d += 6;
            float h = fmaxf(Al[j][c] + Dl[d][c] + bi[c], 0.f);
            v[q] = fmaf(h, sc[c], sh[c]);
        }
        __builtin_nontemporal_store(v, (fvec4*)(ob + idx0));
    }
}

extern "C" void kernel_launch(void* const* d_in, const int* in_sizes, int n_in,
                              void* d_out, int out_size, void* d_ws, size_t ws_size,
                              hipStream_t stream) {
    const float* x      = (const float*)d_in[0];
    const float* conv_w = (const float*)d_in[1];
    const float* conv_b = (const float*)d_in[2];
    const float* gamma  = (const float*)d_in[3];
    const float* beta   = (const float*)d_in[4];
    float* out = (float*)d_out;

    char* ws = (char*)d_ws;
    unsigned short* wbf = (unsigned short*)ws;                       // 512 KB
    unsigned short* AD  = (unsigned short*)(ws + 524288);            // 25165824 B
    float* stats        = (float*)(ws + 524288 + 25165824);          // 2 KB

    k_pre<<<256, 256, 0, stream>>>(conv_w, wbf, stats);
    k_gemm_fused<<<256, 512, 0, stream>>>(x, wbf, conv_b, AD, stats);
    k_out<<<4096, 256, 0, stream>>>(AD, conv_b, gamma, beta, stats, out);
}